// Round 10
// baseline (181.438 us; speedup 1.0000x reference)
//
#include <hip/hip_runtime.h>
#include <math.h>
#include <limits.h>

#define D 128
#define NSUBJ 16
#define MAXN 640        // bucket stride; groups ~512 +- 22 (~6 sigma safety)
#define MARGIN 0.8f
#define PRB 32          // rows per prep slice
#define TI 16           // i-rows per triplet stripe (one MFMA row-tile)
#define TJ 64           // j-cols per tile (4 waves x 16)
#define NSTRIPE 32      // stripes per subject
#define NBLK (NSUBJ * NSTRIPE)   // 512 blocks; bids 0..255 are also prep producers
#define READY_MAGIC 0x1F2E3D4C

typedef __attribute__((ext_vector_type(8))) short bf16x8;
typedef __attribute__((ext_vector_type(4))) float f32x4;

static __device__ __forceinline__ short f2bf(float f) {
    union { float f; unsigned u; } v; v.f = f;
    unsigned r = v.u + 0x7FFF + ((v.u >> 16) & 1);   // RNE
    return (short)(r >> 16);
}

// Load one j-tile's B fragment + column meta into NAMED registers
// (compile-time indices only — dynamic VGPR indexing demotes to scratch: R8 bug).
#define LOADTILE(B0, B1, B2, B3, MI, ML, MS, JT)                         \
    do {                                                                 \
        int jl_ = (JT) * TJ + w * 16 + c, cl_ = min(jl_, n - 1);         \
        const short* rp_ = ebf + (size_t)(base + cl_) * D;               \
        B0 = *(const bf16x8*)&rp_[q * 8];                                \
        B1 = *(const bf16x8*)&rp_[32 + q * 8];                           \
        B2 = *(const bf16x8*)&rp_[64 + q * 8];                           \
        B3 = *(const bf16x8*)&rp_[96 + q * 8];                           \
        int4 m_ = pmeta[base + cl_];                                     \
        MI = (jl_ < n) ? m_.y : -1; ML = m_.x; MS = __int_as_float(m_.z);\
    } while (0)

#define STEP(B0, B1, B2, B3, MI, ML, MS)                                 \
    do {                                                                 \
        f32x4 acc = {0.f, 0.f, 0.f, 0.f};                                \
        acc = __builtin_amdgcn_mfma_f32_16x16x32_bf16(afr[0], B0, acc, 0, 0, 0); \
        acc = __builtin_amdgcn_mfma_f32_16x16x32_bf16(afr[1], B1, acc, 0, 0, 0); \
        acc = __builtin_amdgcn_mfma_f32_16x16x32_bf16(afr[2], B2, acc, 0, 0, 0); \
        acc = __builtin_amdgcn_mfma_f32_16x16x32_bf16(afr[3], B3, acc, 0, 0, 0); \
        if ((MI) >= 0) {                                                 \
            _Pragma("unroll")                                            \
            for (int r = 0; r < 4; ++r) {                                \
                float v = fmaf(-2.f, acc[r], (MS));                      \
                if ((ML) == li[r]) {                                     \
                    if ((MI) != gI[r] && (v > vP[r] ||                   \
                        (v == vP[r] && (unsigned)(MI) < (unsigned)iP[r]))) { \
                        vP[r] = v; iP[r] = (MI);                         \
                    }                                                    \
                } else if (v < vN[r] ||                                  \
                           (v == vN[r] && (unsigned)(MI) < (unsigned)iN[r])) { \
                    vN[r] = v; iN[r] = (MI);                             \
                }                                                        \
            }                                                            \
        }                                                                \
    } while (0)

// ONE dispatch: in-kernel init gate -> prep (bids < nprep) -> device barrier
// -> MFMA Gram + fused hardest-pos/neg selection -> ticket finalize.
// Deadlock-safety without cooperative launch: consumer-only bids (>= nprep)
// are dispatched after producer bids 0..nprep-1; even at 1 block/CU the 256
// producers are co-resident, finish phase A, and release the barrier.
__global__ __launch_bounds__(256, 2) void mega(
        const float* __restrict__ emb, const int* __restrict__ labels,
        const int* __restrict__ sbj,
        int* __restrict__ counts, float* __restrict__ loss_sum,
        int* __restrict__ valid_cnt, int* __restrict__ done,
        int* __restrict__ arrive, int* __restrict__ ready,
        int4* __restrict__ pmeta, short* __restrict__ ebf,
        float* __restrict__ out, int B) {
    const int bid = blockIdx.x, t = threadIdx.x;
    const int nprep = B / PRB;                  // 256

    // ---- init gate: block 0 zeroes control words, everyone waits on magic ----
    if (bid == 0 && t == 0) {
        for (int k = 0; k < NSUBJ; ++k) counts[k] = 0;
        *loss_sum = 0.f; *valid_cnt = 0; *done = 0; *arrive = 0;
        __hip_atomic_store(ready, READY_MAGIC, __ATOMIC_RELEASE,
                           __HIP_MEMORY_SCOPE_AGENT);
    }
    if (t == 0) {
        while (__hip_atomic_load(ready, __ATOMIC_ACQUIRE,
                                 __HIP_MEMORY_SCOPE_AGENT) != READY_MAGIC)
            __builtin_amdgcn_s_sleep(1);
    }
    __syncthreads();

    // ---- phase A: prep slice bid (fixed-stride buckets, bf16 copy, meta) ----
    if (bid < nprep) {
        __shared__ int s_cnt[NSUBJ], s_base[NSUBJ], s_slot[PRB];
        if (t < NSUBJ) s_cnt[t] = 0;
        __syncthreads();
        int s = 0, mypos = 0;
        if (t < PRB) { s = sbj[bid * PRB + t]; mypos = atomicAdd(&s_cnt[s], 1); }
        __syncthreads();
        if (t < NSUBJ) s_base[t] = atomicAdd(&counts[t], s_cnt[t]);
        __syncthreads();
        if (t < PRB) {
            int pos = s_base[s] + mypos;
            s_slot[t] = (pos < MAXN) ? (s * MAXN + pos) : -1;  // never fires at 6 sigma
        }
        __syncthreads();
#pragma unroll
        for (int it = 0; it < (PRB * 16) / 256; ++it) {        // 2 iters: 16 rows x 16 thr
            int lin = it * 256 + t;
            int row = lin >> 4, u = lin & 15;
            int i = bid * PRB + row;
            int slot = s_slot[row];
            const float4* rp = (const float4*)(emb + (size_t)i * D);
            float4 a0 = rp[u * 2], a1 = rp[u * 2 + 1];
            float ssq = 0.f;
            ssq = fmaf(a0.x, a0.x, ssq); ssq = fmaf(a0.y, a0.y, ssq);
            ssq = fmaf(a0.z, a0.z, ssq); ssq = fmaf(a0.w, a0.w, ssq);
            ssq = fmaf(a1.x, a1.x, ssq); ssq = fmaf(a1.y, a1.y, ssq);
            ssq = fmaf(a1.z, a1.z, ssq); ssq = fmaf(a1.w, a1.w, ssq);
#pragma unroll
            for (int off = 8; off > 0; off >>= 1) ssq += __shfl_down(ssq, off, 16);
            ssq = __shfl(ssq, 0, 16);
            if (slot >= 0) {
                bf16x8 pk;
                pk[0] = f2bf(a0.x); pk[1] = f2bf(a0.y); pk[2] = f2bf(a0.z); pk[3] = f2bf(a0.w);
                pk[4] = f2bf(a1.x); pk[5] = f2bf(a1.y); pk[6] = f2bf(a1.z); pk[7] = f2bf(a1.w);
                *(bf16x8*)&ebf[(size_t)slot * D + u * 8] = pk;
                if (u == 0)
                    pmeta[slot] = make_int4(labels[i], i, __float_as_int(ssq), 0);
            }
        }
        __syncthreads();             // all block stores drained (barrier waitcnt)
        if (t == 0) {
            __threadfence();         // device-scope release: write back to LLC
            __hip_atomic_fetch_add(arrive, 1, __ATOMIC_RELEASE,
                                   __HIP_MEMORY_SCOPE_AGENT);
        }
    }

    // ---- device barrier: wait for all prep producers ----
    if (t == 0) {
        while (__hip_atomic_load(arrive, __ATOMIC_ACQUIRE,
                                 __HIP_MEMORY_SCOPE_AGENT) < nprep)
            __builtin_amdgcn_s_sleep(1);
        __threadfence();             // acquire: invalidate stale cached lines
    }
    __syncthreads();

    // ---- phase C: MFMA Gram + fused selection (R9 body, unchanged) ----
    const int s = bid & 15;              // subject -> XCD s%8 (blocks 16k+s pinned)
    const int stripe = bid >> 4;         // 0..31
    const int base = s * MAXN;
    const int n = min(counts[s], MAXN);
    const int lane = t & 63, w = t >> 6, c = lane & 15, q = lane >> 4;

    __shared__ float svP[TI][4]; __shared__ int siP[TI][4];
    __shared__ float svN[TI][4]; __shared__ int siN[TI][4];

    float blockSum = 0.f; int blockCnt = 0;

    for (int i0 = stripe * TI; i0 < n; i0 += NSTRIPE * TI) {
        const int nrows = min(TI, n - i0);
        __syncthreads();                 // sv* scratch free for reuse

        bf16x8 afr[4];
        {
            const short* ap = ebf + (size_t)(base + i0 + min(c, nrows - 1)) * D;
#pragma unroll
            for (int st = 0; st < 4; ++st)
                afr[st] = *(const bf16x8*)&ap[st * 32 + q * 8];
        }
        int li[4], gI[4];
#pragma unroll
        for (int r = 0; r < 4; ++r) {
            int row = q * 4 + r;
            if (row < nrows) { int4 m = pmeta[base + i0 + row]; li[r] = m.x; gI[r] = m.y; }
            else             { li[r] = INT_MIN; gI[r] = -1; }
        }

        float vP[4], vN[4]; int iP[4], iN[4];
#pragma unroll
        for (int r = 0; r < 4; ++r) {
            vP[r] = -INFINITY; iP[r] = -1;
            vN[r] =  INFINITY; iN[r] = -1;
        }

        const int ntiles = (n + TJ - 1) / TJ;
        bf16x8 b00, b01, b02, b03, b10, b11, b12, b13;
        int mi0 = -1, ml0 = INT_MIN, mi1 = -1, ml1 = INT_MIN;
        float ms0 = 0.f, ms1 = 0.f;
        if (0 < ntiles) LOADTILE(b00, b01, b02, b03, mi0, ml0, ms0, 0);
        if (1 < ntiles) LOADTILE(b10, b11, b12, b13, mi1, ml1, ms1, 1);

        for (int jt = 0; jt < ntiles; jt += 2) {
            {   // even tile: consume buffer 0, refill for jt+2
                bf16x8 c0 = b00, c1 = b01, c2 = b02, c3 = b03;
                int cmi = mi0, cml = ml0; float cms = ms0;
                if (jt + 2 < ntiles) LOADTILE(b00, b01, b02, b03, mi0, ml0, ms0, jt + 2);
                STEP(c0, c1, c2, c3, cmi, cml, cms);
            }
            if (jt + 1 < ntiles) {   // odd tile: consume buffer 1, refill for jt+3
                bf16x8 c0 = b10, c1 = b11, c2 = b12, c3 = b13;
                int cmi = mi1, cml = ml1; float cms = ms1;
                if (jt + 3 < ntiles) LOADTILE(b10, b11, b12, b13, mi1, ml1, ms1, jt + 3);
                STEP(c0, c1, c2, c3, cmi, cml, cms);
            }
        }

        // reduce across the 16 col-lanes (tie-break: smallest original index)
#pragma unroll
        for (int off = 8; off > 0; off >>= 1) {
#pragma unroll
            for (int r = 0; r < 4; ++r) {
                float ov = __shfl_down(vP[r], off, 16);
                int   oi = __shfl_down(iP[r], off, 16);
                if (ov > vP[r] || (ov == vP[r] && (unsigned)oi < (unsigned)iP[r])) {
                    vP[r] = ov; iP[r] = oi;
                }
                float on = __shfl_down(vN[r], off, 16);
                int   oj = __shfl_down(iN[r], off, 16);
                if (on < vN[r] || (on == vN[r] && (unsigned)oj < (unsigned)iN[r])) {
                    vN[r] = on; iN[r] = oj;
                }
            }
        }
        if (c == 0) {
#pragma unroll
            for (int r = 0; r < 4; ++r) {
                int row = q * 4 + r;
                svP[row][w] = vP[r]; siP[row][w] = iP[r];
                svN[row][w] = vN[r]; siN[row][w] = iN[r];
            }
        }
        __syncthreads();

        // per-row combine + loss directly from d2:
        // d2 = (sq_j - 2 dot) + sq_i ; dap/dan = sqrt(max(d2,0))
        if (t < TI) {
            float bp = svP[t][0]; int ip = siP[t][0];
            float bn = svN[t][0]; int in_ = siN[t][0];
#pragma unroll
            for (int ww = 1; ww < 4; ++ww) {
                float o = svP[t][ww]; int oi = siP[t][ww];
                if (o > bp || (o == bp && (unsigned)oi < (unsigned)ip)) { bp = o; ip = oi; }
                float on = svN[t][ww]; int oj = siN[t][ww];
                if (on < bn || (on == bn && (unsigned)oj < (unsigned)in_)) { bn = on; in_ = oj; }
            }
            bool valid = (t < nrows) && (ip >= 0) && (in_ >= 0);
            float sqi = __int_as_float(pmeta[base + i0 + min(t, nrows - 1)].z);
            float per = 0.f;
            if (valid) {
                float dap = sqrtf(fmaxf(bp + sqi, 0.f));
                float dan = sqrtf(fmaxf(bn + sqi, 0.f));
                per = fmaxf(dap - dan + MARGIN, 0.f);
            }
            int vc = valid ? 1 : 0;
#pragma unroll
            for (int off = 8; off > 0; off >>= 1) {   // t<16 are lanes 0..15 of wave 0
                per += __shfl_down(per, off, 16);
                vc  += __shfl_down(vc,  off, 16);
            }
            if (t == 0) { blockSum += per; blockCnt += vc; }
        }
    }

    // ---- ticket finalize: last block writes the mean ----
    if (t == 0) {
        if (blockCnt > 0) {
            atomicAdd(loss_sum, blockSum);
            atomicAdd(valid_cnt, blockCnt);
        }
        __threadfence();
        int ticket = atomicAdd(done, 1);
        if (ticket == NBLK - 1) {
            float sum = atomicAdd(loss_sum, 0.0f);
            int   cnt = atomicAdd(valid_cnt, 0);
            out[0] = (cnt > 0) ? (sum / (float)cnt) : 0.0f;
        }
    }
}

extern "C" void kernel_launch(void* const* d_in, const int* in_sizes, int n_in,
                              void* d_out, int out_size, void* d_ws, size_t ws_size,
                              hipStream_t stream) {
    const float* emb    = (const float*)d_in[0];
    const int*   labels = (const int*)d_in[1];
    const int*   sbj    = (const int*)d_in[2];
    float*       out    = (float*)d_out;
    int B = in_sizes[1];   // 8192

    // Workspace (poisoned 0xAA each call; zeroed in-kernel via ready gate):
    //   [0,64)   int counts[16]
    //   [64,68)  float loss_sum  [72,76) int valid_cnt  [80,84) int done
    //   [88,92)  int arrive      [96,100) int ready
    //   [128, +NSUBJ*MAXN*16)  int4 pmeta
    //   [256-align, +NSUBJ*MAXN*D*2) short ebf (~2.62 MB)
    char*  ws        = (char*)d_ws;
    int*   counts    = (int*)ws;
    float* loss_sum  = (float*)(ws + 64);
    int*   valid_cnt = (int*)(ws + 72);
    int*   done      = (int*)(ws + 80);
    int*   arrive    = (int*)(ws + 88);
    int*   ready     = (int*)(ws + 96);
    int4*  pmeta     = (int4*)(ws + 128);
    size_t ebf_off   = (128 + (size_t)NSUBJ * MAXN * sizeof(int4) + 255) & ~(size_t)255;
    short* ebf       = (short*)(ws + ebf_off);

    mega<<<NBLK, 256, 0, stream>>>(emb, labels, sbj, counts, loss_sum, valid_cnt,
                                   done, arrive, ready, pmeta, ebf, out, B);
}

// Round 11
// 105.457 us; speedup vs baseline: 1.7205x; 1.7205x over previous
//
#include <hip/hip_runtime.h>
#include <math.h>
#include <limits.h>

#define D 128
#define NSUBJ 16
#define MAXN 640        // bucket stride; groups ~512 +- 22 (~6 sigma safety)
#define MARGIN 0.8f
#define PRB 32          // rows per prep block
#define TI 16           // i-rows per triplet block (one MFMA row-tile)
#define TJ 64           // j-cols per tile (4 waves x 16)
#define NSTRIPE 32      // stripes per subject
#define NBLK (NSUBJ * NSTRIPE)   // 512 blocks = 2/CU

typedef __attribute__((ext_vector_type(8))) short bf16x8;
typedef __attribute__((ext_vector_type(4))) float f32x4;

static __device__ __forceinline__ short f2bf(float f) {
    union { float f; unsigned u; } v; v.f = f;
    unsigned r = v.u + 0x7FFF + ((v.u >> 16) & 1);   // RNE
    return (short)(r >> 16);
}

// prep: fixed-stride per-subject buckets (slot = s*MAXN + pos) + fp32->bf16
// permuted copy + packed meta {label, orig idx, sq-norm}. Parallel across grid.
__global__ __launch_bounds__(256) void prep_kernel(
        const float* __restrict__ emb, const int* __restrict__ labels,
        const int* __restrict__ sbj, int* __restrict__ counts,
        int4* __restrict__ pmeta, short* __restrict__ ebf, int B) {
    __shared__ int s_cnt[NSUBJ], s_base[NSUBJ], s_slot[PRB];
    const int t = threadIdx.x, bid = blockIdx.x;
    if (t < NSUBJ) s_cnt[t] = 0;
    __syncthreads();
    int s = 0, mypos = 0;
    if (t < PRB) { s = sbj[bid * PRB + t]; mypos = atomicAdd(&s_cnt[s], 1); }
    __syncthreads();
    if (t < NSUBJ) s_base[t] = atomicAdd(&counts[t], s_cnt[t]);
    __syncthreads();
    if (t < PRB) {
        int pos = s_base[s] + mypos;
        s_slot[t] = (pos < MAXN) ? (s * MAXN + pos) : -1;   // never fires at 6 sigma
    }
    __syncthreads();
#pragma unroll
    for (int it = 0; it < (PRB * 16) / 256; ++it) {         // 2 iters: 16 rows x 16 thr
        int lin = it * 256 + t;
        int row = lin >> 4, u = lin & 15;
        int i = bid * PRB + row;
        int slot = s_slot[row];
        const float4* rp = (const float4*)(emb + (size_t)i * D);
        float4 a0 = rp[u * 2], a1 = rp[u * 2 + 1];
        float ssq = 0.f;
        ssq = fmaf(a0.x, a0.x, ssq); ssq = fmaf(a0.y, a0.y, ssq);
        ssq = fmaf(a0.z, a0.z, ssq); ssq = fmaf(a0.w, a0.w, ssq);
        ssq = fmaf(a1.x, a1.x, ssq); ssq = fmaf(a1.y, a1.y, ssq);
        ssq = fmaf(a1.z, a1.z, ssq); ssq = fmaf(a1.w, a1.w, ssq);
#pragma unroll
        for (int off = 8; off > 0; off >>= 1) ssq += __shfl_down(ssq, off, 16);
        // lane u==0 of each 16-group holds the total; no broadcast needed
        if (slot >= 0) {
            bf16x8 pk;
            pk[0] = f2bf(a0.x); pk[1] = f2bf(a0.y); pk[2] = f2bf(a0.z); pk[3] = f2bf(a0.w);
            pk[4] = f2bf(a1.x); pk[5] = f2bf(a1.y); pk[6] = f2bf(a1.z); pk[7] = f2bf(a1.w);
            *(bf16x8*)&ebf[(size_t)slot * D + u * 8] = pk;
            if (u == 0)
                pmeta[slot] = make_int4(labels[i], i, __float_as_int(ssq), 0);
        }
    }
}

// Load one j-tile's B fragment + column meta into NAMED registers
// (compile-time indices only — dynamic VGPR indexing demotes to scratch: R8 bug).
#define LOADTILE(B0, B1, B2, B3, MI, ML, MS, JT)                         \
    do {                                                                 \
        int jl_ = (JT) * TJ + w * 16 + c, cl_ = min(jl_, n - 1);         \
        const short* rp_ = ebf + (size_t)(base + cl_) * D;               \
        B0 = *(const bf16x8*)&rp_[q * 8];                                \
        B1 = *(const bf16x8*)&rp_[32 + q * 8];                           \
        B2 = *(const bf16x8*)&rp_[64 + q * 8];                           \
        B3 = *(const bf16x8*)&rp_[96 + q * 8];                           \
        int4 m_ = pmeta[base + cl_];                                     \
        MI = (jl_ < n) ? m_.y : -1; ML = m_.x; MS = __int_as_float(m_.z);\
    } while (0)

// Selection: NO per-element tie-break needed — within a lane j is scanned in
// ascending order, so strict >/< already keeps the smallest index on ties.
// Cross-lane reduces below retain explicit tie-breaks (exact jnp semantics).
#define STEP(B0, B1, B2, B3, MI, ML, MS)                                 \
    do {                                                                 \
        f32x4 acc = {0.f, 0.f, 0.f, 0.f};                                \
        acc = __builtin_amdgcn_mfma_f32_16x16x32_bf16(afr[0], B0, acc, 0, 0, 0); \
        acc = __builtin_amdgcn_mfma_f32_16x16x32_bf16(afr[1], B1, acc, 0, 0, 0); \
        acc = __builtin_amdgcn_mfma_f32_16x16x32_bf16(afr[2], B2, acc, 0, 0, 0); \
        acc = __builtin_amdgcn_mfma_f32_16x16x32_bf16(afr[3], B3, acc, 0, 0, 0); \
        if ((MI) >= 0) {                                                 \
            _Pragma("unroll")                                            \
            for (int r = 0; r < 4; ++r) {                                \
                float v = fmaf(-2.f, acc[r], (MS));                      \
                if ((ML) == li[r]) {                                     \
                    if ((MI) != gI[r] && v > vP[r]) { vP[r] = v; iP[r] = (MI); } \
                } else if (v < vN[r]) { vN[r] = v; iN[r] = (MI); }       \
            }                                                            \
        }                                                                \
    } while (0)

// triplet: MFMA Gram + fused hardest-pos/neg selection; loss computed directly
// from selection d2 values (no second distance pass). Ticket finalize.
__global__ __launch_bounds__(256) void triplet_kernel(
        const short* __restrict__ ebf, const int4* __restrict__ pmeta,
        const int* __restrict__ counts,
        float* __restrict__ loss_sum, int* __restrict__ valid_cnt,
        int* __restrict__ done, float* __restrict__ out) {
    const int bid = blockIdx.x, t = threadIdx.x;
    const int s = bid & 15;              // subject -> XCD s%8 (blocks 16k+s pinned)
    const int stripe = bid >> 4;         // 0..31
    const int base = s * MAXN;
    const int n = min(counts[s], MAXN);
    const int lane = t & 63, w = t >> 6, c = lane & 15, q = lane >> 4;

    __shared__ float svP[TI][4]; __shared__ int siP[TI][4];
    __shared__ float svN[TI][4]; __shared__ int siN[TI][4];

    float blockSum = 0.f; int blockCnt = 0;

    for (int i0 = stripe * TI; i0 < n; i0 += NSTRIPE * TI) {
        const int nrows = min(TI, n - i0);

        // A fragments (row = i0 + c) + i-row meta for this lane's 4 output rows
        bf16x8 afr[4];
        {
            const short* ap = ebf + (size_t)(base + i0 + min(c, nrows - 1)) * D;
#pragma unroll
            for (int st = 0; st < 4; ++st)
                afr[st] = *(const bf16x8*)&ap[st * 32 + q * 8];
        }
        int li[4], gI[4];
#pragma unroll
        for (int r = 0; r < 4; ++r) {
            int row = q * 4 + r;
            if (row < nrows) { int4 m = pmeta[base + i0 + row]; li[r] = m.x; gI[r] = m.y; }
            else             { li[r] = INT_MIN; gI[r] = -1; }
        }

        float vP[4], vN[4]; int iP[4], iN[4];
#pragma unroll
        for (int r = 0; r < 4; ++r) {
            vP[r] = -INFINITY; iP[r] = -1;
            vN[r] =  INFINITY; iN[r] = -1;
        }

        const int ntiles = (n + TJ - 1) / TJ;
        // ---- 2-deep pipeline, explicit named buffers, manual 2x unroll ----
        bf16x8 b00, b01, b02, b03, b10, b11, b12, b13;
        int mi0 = -1, ml0 = INT_MIN, mi1 = -1, ml1 = INT_MIN;
        float ms0 = 0.f, ms1 = 0.f;
        if (0 < ntiles) LOADTILE(b00, b01, b02, b03, mi0, ml0, ms0, 0);
        if (1 < ntiles) LOADTILE(b10, b11, b12, b13, mi1, ml1, ms1, 1);

        for (int jt = 0; jt < ntiles; jt += 2) {
            {   // even tile: consume buffer 0, refill for jt+2
                bf16x8 c0 = b00, c1 = b01, c2 = b02, c3 = b03;
                int cmi = mi0, cml = ml0; float cms = ms0;
                if (jt + 2 < ntiles) LOADTILE(b00, b01, b02, b03, mi0, ml0, ms0, jt + 2);
                STEP(c0, c1, c2, c3, cmi, cml, cms);
            }
            if (jt + 1 < ntiles) {   // odd tile: consume buffer 1, refill for jt+3
                bf16x8 c0 = b10, c1 = b11, c2 = b12, c3 = b13;
                int cmi = mi1, cml = ml1; float cms = ms1;
                if (jt + 3 < ntiles) LOADTILE(b10, b11, b12, b13, mi1, ml1, ms1, jt + 3);
                STEP(c0, c1, c2, c3, cmi, cml, cms);
            }
        }

        // reduce across the 16 col-lanes (tie-break: smallest original index)
#pragma unroll
        for (int off = 8; off > 0; off >>= 1) {
#pragma unroll
            for (int r = 0; r < 4; ++r) {
                float ov = __shfl_down(vP[r], off, 16);
                int   oi = __shfl_down(iP[r], off, 16);
                if (ov > vP[r] || (ov == vP[r] && (unsigned)oi < (unsigned)iP[r])) {
                    vP[r] = ov; iP[r] = oi;
                }
                float on = __shfl_down(vN[r], off, 16);
                int   oj = __shfl_down(iN[r], off, 16);
                if (on < vN[r] || (on == vN[r] && (unsigned)oj < (unsigned)iN[r])) {
                    vN[r] = on; iN[r] = oj;
                }
            }
        }
        if (c == 0) {
#pragma unroll
            for (int r = 0; r < 4; ++r) {
                int row = q * 4 + r;
                svP[row][w] = vP[r]; siP[row][w] = iP[r];
                svN[row][w] = vN[r]; siN[row][w] = iN[r];
            }
        }
        __syncthreads();

        // per-row combine + loss directly from d2 (no second distance pass):
        // d2 = (sq_j - 2 dot) + sq_i ; dap/dan = sqrt(max(d2,0))
        if (t < TI) {
            float bp = svP[t][0]; int ip = siP[t][0];
            float bn = svN[t][0]; int in_ = siN[t][0];
#pragma unroll
            for (int ww = 1; ww < 4; ++ww) {
                float o = svP[t][ww]; int oi = siP[t][ww];
                if (o > bp || (o == bp && (unsigned)oi < (unsigned)ip)) { bp = o; ip = oi; }
                float on = svN[t][ww]; int oj = siN[t][ww];
                if (on < bn || (on == bn && (unsigned)oj < (unsigned)in_)) { bn = on; in_ = oj; }
            }
            bool valid = (t < nrows) && (ip >= 0) && (in_ >= 0);
            float sqi = __int_as_float(pmeta[base + i0 + min(t, nrows - 1)].z);
            float per = 0.f;
            if (valid) {
                float dap = sqrtf(fmaxf(bp + sqi, 0.f));
                float dan = sqrtf(fmaxf(bn + sqi, 0.f));
                per = fmaxf(dap - dan + MARGIN, 0.f);
            }
            int vc = valid ? 1 : 0;
#pragma unroll
            for (int off = 8; off > 0; off >>= 1) {   // t<16 are lanes 0..15 of wave 0
                per += __shfl_down(per, off, 16);
                vc  += __shfl_down(vc,  off, 16);
            }
            if (t == 0) { blockSum += per; blockCnt += vc; }
        }
        if (i0 + NSTRIPE * TI < n) __syncthreads();   // barrier only if another stripe
    }

    // ---- ticket finalize: last block writes the mean ----
    if (t == 0) {
        if (blockCnt > 0) {
            atomicAdd(loss_sum, blockSum);
            atomicAdd(valid_cnt, blockCnt);
        }
        __threadfence();
        int ticket = atomicAdd(done, 1);
        if (ticket == NBLK - 1) {
            float sum = atomicAdd(loss_sum, 0.0f);
            int   cnt = atomicAdd(valid_cnt, 0);
            out[0] = (cnt > 0) ? (sum / (float)cnt) : 0.0f;
        }
    }
}

extern "C" void kernel_launch(void* const* d_in, const int* in_sizes, int n_in,
                              void* d_out, int out_size, void* d_ws, size_t ws_size,
                              hipStream_t stream) {
    const float* emb    = (const float*)d_in[0];
    const int*   labels = (const int*)d_in[1];
    const int*   sbj    = (const int*)d_in[2];
    float*       out    = (float*)d_out;
    int B = in_sizes[1];   // 8192

    // Workspace:
    //   [0,64)   int counts[16]
    //   [64,68)  float loss_sum  [72,76) int valid_cnt  [80,84) int done
    //   [128, +NSUBJ*MAXN*16)  int4 pmeta
    //   [256-align, +NSUBJ*MAXN*D*2) short ebf (~2.62 MB)
    char*  ws        = (char*)d_ws;
    int*   counts    = (int*)ws;
    float* loss_sum  = (float*)(ws + 64);
    int*   valid_cnt = (int*)(ws + 72);
    int*   done      = (int*)(ws + 80);
    int4*  pmeta     = (int4*)(ws + 128);
    size_t ebf_off   = (128 + (size_t)NSUBJ * MAXN * sizeof(int4) + 255) & ~(size_t)255;
    short* ebf       = (short*)(ws + ebf_off);

    hipMemsetAsync(ws, 0, 128, stream);
    prep_kernel<<<B / PRB, 256, 0, stream>>>(emb, labels, sbj, counts, pmeta, ebf, B);
    triplet_kernel<<<NBLK, 256, 0, stream>>>(ebf, pmeta, counts,
                                             loss_sum, valid_cnt, done, out);
}